// Round 7
// baseline (330.043 us; speedup 1.0000x reference)
//
#include <hip/hip_runtime.h>
#include <math.h>

#define NT 256
#define NW 4            // waves per block
#define NB 512
#define NP 2000
#define NS 1000
#define NO 50

typedef unsigned int u32;
typedef unsigned long long u64;
typedef unsigned short u16;
typedef unsigned char u8;
typedef __attribute__((ext_vector_type(8))) short short8;
typedef __attribute__((ext_vector_type(4))) float f32x4;

__device__ __forceinline__ float sl1(float x){ float d = fabsf(x); return d < 1.f ? 0.5f*d*d : d - 0.5f; }

__device__ __forceinline__ u32 mono(float f){
  u32 u = __float_as_uint(f);
  return u ^ ((u >> 31) ? 0xFFFFFFFFu : 0x80000000u);
}
// bitwise-exact vs jnp: mul, mul, add, sqrt all RN, no contraction
__device__ __forceinline__ float dist_rn(float x, float y){
  return __fsqrt_rn(__fadd_rn(__fmul_rn(x,x), __fmul_rn(y,y)));
}
__device__ __forceinline__ u16 f2bf(float f){           // RNE f32->bf16
  u32 u = __float_as_uint(f);
  u32 r = (u + 0x7FFFu + ((u >> 16) & 1u)) >> 16;
  return (u16)r;
}
__device__ __forceinline__ float bf2f(u16 h){ return __uint_as_float(((u32)h) << 16); }
// wave-uniform value -> SGPR (saves a VGPR; all callers pass lane-invariant values)
__device__ __forceinline__ float rfl(float v){
  return __builtin_bit_cast(float, __builtin_amdgcn_readfirstlane(__builtin_bit_cast(int, v)));
}

// gelu via Abramowitz-Stegun 7.1.26 erf (|eps| <= 1.5e-7), ~16 VALU
__device__ __forceinline__ float gelu_(float x){
  float z = x * 0.70710678118654752440f;
  float az = fabsf(z);
  float t = __frcp_rn(fmaf(0.3275911f, az, 1.0f));
  float p =          fmaf(t, 1.061405429f, -1.453152027f);
  p = fmaf(p, t, 1.421413741f);
  p = fmaf(p, t, -0.284496736f);
  p = fmaf(p, t, 0.254829592f);
  p = p * t;
  float e = __expf(-az*az);
  float er = fmaf(-p, e, 1.0f);
  er = copysignf(er, z);
  float hx = 0.5f * x;
  return fmaf(hx, er, hx);
}
__device__ __forceinline__ float wred(float v){  // full-wave sum
  #pragma unroll
  for (int s = 1; s < 64; s <<= 1) v += __shfl_xor(v, s, 64);
  return v;
}
__device__ __forceinline__ float bsum(float v, float* s, int tid){
  #pragma unroll
  for (int o = 32; o > 0; o >>= 1) v += __shfl_down(v, o, 64);
  __syncthreads();
  if ((tid & 63) == 0) s[tid >> 6] = v;
  __syncthreads();
  return (s[0]+s[1])+(s[2]+s[3]);
}
__device__ __forceinline__ float bmax(float v, float* s, int tid){
  #pragma unroll
  for (int o = 32; o > 0; o >>= 1) v = fmaxf(v, __shfl_down(v, o, 64));
  __syncthreads();
  if ((tid & 63) == 0) s[tid >> 6] = v;
  __syncthreads();
  return fmaxf(fmaxf(s[0],s[1]), fmaxf(s[2],s[3]));
}
__device__ __forceinline__ u32 bminu32(u32 v, u32* s, int tid){
  #pragma unroll
  for (int o = 32; o > 0; o >>= 1){ u32 w = __shfl_down(v, o, 64); v = w < v ? w : v; }
  __syncthreads();
  if ((tid & 63) == 0) s[tid >> 6] = v;
  __syncthreads();
  u32 a = s[0] < s[1] ? s[0] : s[1];
  u32 c = s[2] < s[3] ? s[2] : s[3];
  return a < c ? a : c;
}
__device__ __forceinline__ u64 bminu64(u64 v, u64* s, int tid){
  #pragma unroll
  for (int o = 32; o > 0; o >>= 1){ u64 w = __shfl_down(v, o, 64); v = w < v ? w : v; }
  __syncthreads();
  if ((tid & 63) == 0) s[tid >> 6] = v;
  __syncthreads();
  u64 a = s[0] < s[1] ? s[0] : s[1];
  u64 c = s[2] < s[3] ? s[2] : s[3];
  return a < c ? a : c;
}

// NOTE: no second __launch_bounds__ arg — on gfx950 it maps to min waves-per-EU
// and halves the unified VGPR/AGPR budget (64-VGPR cap -> 1 GB of spill traffic,
// measured rounds 4-5). Single arg only.
__global__ __launch_bounds__(NT) void main_k(
    const float* __restrict__ osm, const float* __restrict__ agent, const float* __restrict__ vect,
    const float* __restrict__ endp,
    const float* __restrict__ oxw1, const float* __restrict__ oxb1, const float* __restrict__ oxg1, const float* __restrict__ oxbe1,
    const float* __restrict__ oxw2, const float* __restrict__ oxb2,
    const float* __restrict__ tpw1, const float* __restrict__ tpb1, const float* __restrict__ tpg1, const float* __restrict__ tpbe1,
    const float* __restrict__ tpw2, const float* __restrict__ tpb2, const float* __restrict__ tpg2, const float* __restrict__ tpbe2,
    const float* __restrict__ tpw3, const float* __restrict__ tpb3,
    float* __restrict__ out, double* __restrict__ acc, u32* __restrict__ cnt)
{
  const int b = blockIdx.x;
  const int tid = threadIdx.x;
  const int lane = tid & 63;
  const int wv = tid >> 6;
  const int lm = lane & 15;
  const int q  = lane >> 4;

  __shared__ u32 keys32[2048];       // mono(dist to origin) per original point
  __shared__ u8  state[2048];
  __shared__ u32 hist[256];
  __shared__ u32 wtot[NW];
  __shared__ u32 sc[8];              // 0:Krem 1:pivot 2:done 4:cnt 5:picked-s
  __shared__ u16 sIdx[1024];         // compacted s -> original point idx
  __shared__ float2 ptf2[NS];
  __shared__ float2 tg[NS];          // also reused as [8][64] f32 scratch in P1
  __shared__ float pol[NS];
  __shared__ float vfs[64], ats[64];
  __shared__ float4 tabO[64];        // {foxA, foxB, foxC, oxbe1}
  __shared__ float2 tabW[64];        // {w2a, w2b}
  __shared__ float4 tabT[64];        // {ftpA, ftpB, ftpC, tpbe1}
  __shared__ float4 tabE[64];        // {tpg2, tpbe2, tpw3a, tpw3b}   (epilogue, saves 16 VGPRs)
  __shared__ float  tabB2[64];       // tpb2                          (epilogue, saves 4 VGPRs)
  __shared__ float scox[6], sctp[6];
  __shared__ float redf[NW];
  __shared__ u32 redu[NW];
  __shared__ u64 redk[NW];
  __shared__ u16 list50[64];

  const float2* osm2 = (const float2*)osm;
  const float ex = endp[b*2 + 0], ey = endp[b*2 + 1];

  // ---------------- P0: batch vectors, distance keys, state init ----------------
  if (tid < 64){ vfs[tid] = vect[b*64 + tid]; ats[tid] = agent[b*64 + tid]; }
  for (int i = tid; i < NP; i += NT){
    float2 P = osm2[((size_t)b*NP + i)*2];
    keys32[i] = mono(dist_rn(P.x, P.y));
  }
  for (int i = tid; i < 2048; i += NT) state[i] = (i < NP) ? (u8)2 : (u8)0;
  if (tid == 0){ sc[0] = NS; sc[2] = 0; }
  __syncthreads();

  // ---------------- P1: bo/bt partials (feat = [vf, at], 4 groups x 32 k) ----------------
  {
    float* part = (float*)tg;   // [8][64]
    const int ch = tid & 63, grp = tid >> 6;
    float pox = 0.f, ptp = 0.f;
    for (int k = grp*32; k < grp*32 + 32; ++k){
      float f = (k < 64) ? vfs[k] : ats[k-64];
      pox = fmaf(f, oxw1[k*64 + ch], pox);
      ptp = fmaf(f, tpw1[k*64 + ch], ptp);
    }
    part[grp*64 + ch] = pox;
    part[(grp+4)*64 + ch] = ptp;
    __syncthreads();
    // ---------------- P2: closed-form LN folding (wave 0) ----------------
    if (tid < 64){
      float bo = oxb1[tid] + ((part[0*64+tid]+part[1*64+tid])+(part[2*64+tid]+part[3*64+tid]));
      float bt = tpb1[tid] + ((part[4*64+tid]+part[5*64+tid])+(part[6*64+tid]+part[7*64+tid]));
      float cxo = oxw1[128*64 + tid], cyo = oxw1[129*64 + tid];
      float cxt = tpw1[128*64 + tid], cyt = tpw1[129*64 + tid];
      const float inv64 = 1.0f/64.0f;
      float mb = wred(bo)*inv64, mx_ = wred(cxo)*inv64, my_ = wred(cyo)*inv64;
      float e0 = bo - mb, e1 = cxo - mx_, e2 = cyo - my_;
      float g = oxg1[tid];
      tabO[tid] = make_float4(e0*g, e1*g, e2*g, oxbe1[tid]);
      tabW[tid] = make_float2(oxw2[2*tid], oxw2[2*tid + 1]);
      tabE[tid] = make_float4(tpg2[tid], tpbe2[tid], tpw3[2*tid], tpw3[2*tid + 1]);
      tabB2[tid] = tpb2[tid];
      float E00 = wred(e0*e0)*inv64, E11 = wred(e1*e1)*inv64, E22 = wred(e2*e2)*inv64;
      float E01 = wred(e0*e1)*inv64, E02 = wred(e0*e2)*inv64, E12 = wred(e1*e2)*inv64;
      if (tid == 0){ scox[0]=E00; scox[1]=E11; scox[2]=E22; scox[3]=E01; scox[4]=E02; scox[5]=E12; }
      float mb2 = wred(bt)*inv64, mx2 = wred(cxt)*inv64, my2 = wred(cyt)*inv64;
      float f0 = bt - mb2, f1 = cxt - mx2, f2 = cyt - my2;
      float gt_ = tpg1[tid];
      tabT[tid] = make_float4(f0*gt_, f1*gt_, f2*gt_, tpbe1[tid]);
      float F00 = wred(f0*f0)*inv64, F11 = wred(f1*f1)*inv64, F22 = wred(f2*f2)*inv64;
      float F01 = wred(f0*f1)*inv64, F02 = wred(f0*f2)*inv64, F12 = wred(f1*f2)*inv64;
      if (tid == 0){ sctp[0]=F00; sctp[1]=F11; sctp[2]=F22; sctp[3]=F01; sctp[4]=F02; sctp[5]=F12; }
    }
  }
  __syncthreads();

  // ---------------- radix select #1: 1000 smallest by (mono(d), idx) ----------------
  {
    const int plist[6] = {7,6,5,4,1,0};
    for (int pi = 0; pi < 6; ++pi){
      if (sc[2]) break;
      const int p = plist[pi];
      hist[tid] = 0;
      __syncthreads();
      for (int i = tid; i < NP; i += NT) if (state[i] == 2){
        int bb = (p >= 4) ? (int)((keys32[i] >> ((p-4)*8)) & 255) : (int)((((u32)i) >> (p*8)) & 255);
        atomicAdd(&hist[bb], 1u);
      }
      __syncthreads();
      u32 myc = hist[tid], v = myc;
      { int l_ = tid & 63;
        #pragma unroll
        for (int s = 1; s < 64; s <<= 1){ u32 n = __shfl_up(v, s, 64); if (l_ >= s) v += n; }
        if (l_ == 63) wtot[tid >> 6] = v;
      }
      __syncthreads();
      bool iamp = false; u32 nk = 0;
      {
        u32 add = 0;
        #pragma unroll
        for (int w = 0; w < 4; ++w) if (w < (tid >> 6)) add += wtot[w];
        u32 myinc = v + add;
        u32 Krem = sc[0];
        u32 exc = myinc - myc;
        if (myc > 0 && exc <= Krem-1 && Krem-1 < myinc){ sc[1] = (u32)tid; iamp = true; nk = Krem - exc; }
      }
      __syncthreads();
      u32 pb = sc[1];
      for (int i = tid; i < NP; i += NT) if (state[i] == 2){
        int bb = (p >= 4) ? (int)((keys32[i] >> ((p-4)*8)) & 255) : (int)((((u32)i) >> (p*8)) & 255);
        state[i] = (bb < (int)pb) ? (u8)1 : (bb > (int)pb) ? (u8)0 : (u8)2;
      }
      if (iamp){ sc[0] = nk; if (nk == myc) sc[2] = 1; }
      __syncthreads();
    }
    // compact (selected = state != 0); order arbitrary by design
    if (tid == 0) sc[4] = 0;
    __syncthreads();
    for (int i = tid; i < NP; i += NT) if (state[i] != 0){
      u32 pos = atomicAdd(&sc[4], 1u);
      sIdx[pos] = (u16)i;
      ptf2[pos] = osm2[((size_t)b*NP + i)*2];
    }
    __syncthreads();
  }

  // ---------------- phase-2 wave-uniform scalars -> SGPRs ----------------
  const float so0 = rfl(scox[0]), so1 = rfl(scox[1]), so2 = rfl(scox[2]), so3 = rfl(scox[3]), so4 = rfl(scox[4]), so5 = rfl(scox[5]);
  const float st0 = rfl(sctp[0]), st1 = rfl(sctp[1]), st2 = rfl(sctp[2]), st3 = rfl(sctp[3]), st4 = rfl(sctp[4]), st5 = rfl(sctp[5]);
  const float oxb20 = rfl(oxb2[0]), oxb21 = rfl(oxb2[1]), tpb30 = rfl(tpb3[0]), tpb31 = rfl(tpb3[1]);
  // B fragments of tpw2 (split bf16: Bh + Bl), resident in VGPRs
  short8 bh[2][4], bl[2][4];
  #pragma unroll
  for (int kt = 0; kt < 2; ++kt)
    #pragma unroll
    for (int nt = 0; nt < 4; ++nt){
      short8 H, L;
      #pragma unroll
      for (int j = 0; j < 8; ++j){
        float w = tpw2[(kt*32 + q*8 + j)*64 + nt*16 + lm];
        u16 hh = f2bf(w);
        H[j] = (short)hh;
        L[j] = (short)f2bf(w - bf2f(hh));
      }
      bh[kt][nt] = H; bl[kt][nt] = L;
    }

  // ---------------- phase 2: MLP, A-layout direct (tile of 16 points / wave-iter) ----------------
  float loff = 0.f;
  for (int t = wv; t < 63; t += NW){
    const int pbase = t*16;
    int sp = pbase + lm; if (sp > NS-1) sp = NS-1;
    const float2 P = ptf2[sp];
    const float px = P.x, py = P.y;
    // ox layer: closed-form LN; lane computes channels q*16..q*16+15 for its point lm
    float var1 = so0 + px*px*so1 + py*py*so2 + 2.0f*(px*so3 + py*so4 + px*py*so5);
    const float r1 = __frsqrt_rn(var1 + 1e-5f);
    float o0 = 0.f, o1 = 0.f;
    #pragma unroll
    for (int j = 0; j < 16; ++j){
      const int c = q*16 + j;
      const float4 T = tabO[c];
      const float2 W = tabW[c];
      float g1 = gelu_(fmaf(r1, fmaf(py, T.z, fmaf(px, T.y, T.x)), T.w));
      o0 = fmaf(g1, W.x, o0);
      o1 = fmaf(g1, W.y, o1);
    }
    o0 += __shfl_xor(o0,16,64); o0 += __shfl_xor(o0,32,64);
    o1 += __shfl_xor(o1,16,64); o1 += __shfl_xor(o1,32,64);
    const float tx = px + o0 + oxb20;
    const float ty = py + o1 + oxb21;
    // tp layer1: lane computes exactly its A-fragment channels (q*8+j and 32+q*8+j)
    float var2 = st0 + tx*tx*st1 + ty*ty*st2 + 2.0f*(tx*st3 + ty*st4 + tx*ty*st5);
    const float r2 = __frsqrt_rn(var2 + 1e-5f);
    short8 ah0, ah1, al0, al1;
    #pragma unroll
    for (int j = 0; j < 8; ++j){
      const int c0 = q*8 + j, c1 = 32 + q*8 + j;
      const float4 T0 = tabT[c0], T1 = tabT[c1];
      float v0 = gelu_(fmaf(r2, fmaf(ty, T0.z, fmaf(tx, T0.y, T0.x)), T0.w));
      float v1 = gelu_(fmaf(r2, fmaf(ty, T1.z, fmaf(tx, T1.y, T1.x)), T1.w));
      u16 h0 = f2bf(v0), h1 = f2bf(v1);
      ah0[j] = (short)h0; al0[j] = (short)f2bf(v0 - bf2f(h0));
      ah1[j] = (short)h1; al1[j] = (short)f2bf(v1 - bf2f(h1));
    }
    // 3-term split MFMA: h3 = g2 @ tpw2 + b2
    f32x4 accv[4];
    #pragma unroll
    for (int nt = 0; nt < 4; ++nt){
      const float b2v = tabB2[lm + 16*nt];
      f32x4 c; c[0] = c[1] = c[2] = c[3] = b2v;
      c = __builtin_amdgcn_mfma_f32_16x16x32_bf16(ah0, bh[0][nt], c, 0,0,0);
      c = __builtin_amdgcn_mfma_f32_16x16x32_bf16(ah1, bh[1][nt], c, 0,0,0);
      c = __builtin_amdgcn_mfma_f32_16x16x32_bf16(ah0, bl[0][nt], c, 0,0,0);
      c = __builtin_amdgcn_mfma_f32_16x16x32_bf16(ah1, bl[1][nt], c, 0,0,0);
      c = __builtin_amdgcn_mfma_f32_16x16x32_bf16(al0, bh[0][nt], c, 0,0,0);
      c = __builtin_amdgcn_mfma_f32_16x16x32_bf16(al1, bh[1][nt], c, 0,0,0);
      accv[nt] = c;
    }
    // epilogue in C-layout (row/point = q*4+e, col/channel = lm + 16*nt): LN3 + gelu + tp3
    float sP[4], qP[4];
    #pragma unroll
    for (int e = 0; e < 4; ++e){
      float a0 = accv[0][e], a1 = accv[1][e], a2 = accv[2][e], a3 = accv[3][e];
      sP[e] = (a0+a1)+(a2+a3);
      qP[e] = fmaf(a0,a0, fmaf(a1,a1, fmaf(a2,a2, a3*a3)));
    }
    #pragma unroll
    for (int s_ = 1; s_ < 16; s_ <<= 1){
      #pragma unroll
      for (int e = 0; e < 4; ++e){ sP[e] += __shfl_xor(sP[e], s_, 64); qP[e] += __shfl_xor(qP[e], s_, 64); }
    }
    float mE[4], rE[4];
    #pragma unroll
    for (int e = 0; e < 4; ++e){
      float m = sP[e] * (1.0f/64.0f);
      float vv = fmaf(sP[e], -m*(1.0f/64.0f), qP[e]*(1.0f/64.0f));
      mE[e] = m; rE[e] = __frsqrt_rn(vv + 1e-5f);
    }
    float uo[4] = {0,0,0,0}, vo[4] = {0,0,0,0};
    #pragma unroll
    for (int nt = 0; nt < 4; ++nt){
      const float4 E = tabE[lm + 16*nt];
      #pragma unroll
      for (int e = 0; e < 4; ++e){
        float g = gelu_(fmaf((accv[nt][e]-mE[e])*rE[e], E.x, E.y));
        uo[e] = fmaf(g, E.z, uo[e]);
        vo[e] = fmaf(g, E.w, vo[e]);
      }
    }
    #pragma unroll
    for (int s_ = 1; s_ < 16; s_ <<= 1){
      #pragma unroll
      for (int e = 0; e < 4; ++e){ uo[e] += __shfl_xor(uo[e], s_, 64); vo[e] += __shfl_xor(vo[e], s_, 64); }
    }
    if (lm == 0){
      #pragma unroll
      for (int e = 0; e < 4; ++e){
        int pt = pbase + q*4 + e;
        if (pt < NS){
          float t0 = uo[e] + tpb30, t1 = vo[e] + tpb31;
          tg[pt] = make_float2(t0, t1);
          loff += sl1(t0-ex) + sl1(t1-ey);
        }
      }
    }
  }
  __syncthreads();

  // ---------------- phase 3/4: stats, policy, L_cls ----------------
  const float loffT = bsum(loff, redf, tid);
  float sx = 0.f, sy = 0.f;
  for (int s = tid; s < NS; s += NT){ float2 T = tg[s]; sx += T.x; sy += T.y; }
  const float mx = bsum(sx, redf, tid) * (1.0f/NS);
  const float my = bsum(sy, redf, tid) * (1.0f/NS);
  float qx = 0.f, qy = 0.f;
  for (int s = tid; s < NS; s += NT){ float2 T = tg[s]; float dx = T.x-mx, dy = T.y-my; qx = fmaf(dx,dx,qx); qy = fmaf(dy,dy,qy); }
  const float vx = bsum(qx, redf, tid) * (1.0f/(NS-1));
  const float vy = bsum(qy, redf, tid) * (1.0f/(NS-1));
  const float TWO_PI = 6.2831853071795864769f;
  const float rdx = __frcp_rn(__fsqrt_rn(TWO_PI*vx + 1e-6f));
  const float rdy = __frcp_rn(__fsqrt_rn(TWO_PI*vy + 1e-6f));
  float pmaxl = -1e30f;
  for (int s = tid; s < NS; s += NT){
    float2 T = tg[s]; float dx = T.x-mx, dy = T.y-my;
    float pdx = expf(-0.5f*dx*dx/vx + 1e-6f) * rdx;
    float pdy = expf(-0.5f*dy*dy/vy + 1e-6f) * rdy;
    float pp = pdx*pdy;
    pol[s] = pp;
    pmaxl = fmaxf(pmaxl, pp);
  }
  const float pmax = bmax(pmaxl, redf, tid);
  float se = 0.f;
  for (int s = tid; s < NS; s += NT) se += expf(pol[s] - pmax);
  const float sume = bsum(se, redf, tid);

  // target_index: exact argmax of -d/T with rank tie-break (3 scans)
  u32 xkm = 0xFFFFFFFFu;
  for (int s = tid; s < NS; s += NT){
    float2 Pp = ptf2[s];
    float dd = dist_rn(Pp.x-ex, Pp.y-ey);
    u32 xk = ~mono((0.0f - dd) / 0.01f);
    if (xk < xkm) xkm = xk;
  }
  xkm = bminu32(xkm, redu, tid);
  u64 dmin = 0xFFFFFFFFFFFFFFFFull;
  for (int s = tid; s < NS; s += NT){
    float2 Pp = ptf2[s];
    float dd = dist_rn(Pp.x-ex, Pp.y-ey);
    u32 xk = ~mono((0.0f - dd) / 0.01f);
    if (xk == xkm){ u32 oi = sIdx[s]; u64 dk = (((u64)keys32[oi]) << 32) | (u64)oi; if (dk < dmin) dmin = dk; }
  }
  dmin = bminu64(dmin, redk, tid);
  for (int s = tid; s < NS; s += NT){
    float2 Pp = ptf2[s];
    float dd = dist_rn(Pp.x-ex, Pp.y-ey);
    u32 xk = ~mono((0.0f - dd) / 0.01f);
    u32 oi = sIdx[s];
    if (xk == xkm && ((((u64)keys32[oi]) << 32) | (u64)oi) == dmin) sc[5] = (u32)s;
  }
  __syncthreads();
  if (tid == 0){
    float lse = pmax + logf(sume);
    float picked = pol[sc[5]];
    atomicAdd(&acc[0], (double)(lse - picked));
    atomicAdd(&acc[1], (double)loffT);
  }

  // ---------------- radix select #2: top-50 by (~mono(pol), mono(d), idx) ----------------
  for (int i = tid; i < 2048; i += NT) state[i] = (i < NS) ? (u8)2 : (u8)0;
  if (tid == 0){ sc[0] = NO; sc[2] = 0; }
  __syncthreads();
  {
    const int plist2[10] = {11,10,9,8,7,6,5,4,1,0};
    for (int pi = 0; pi < 10; ++pi){
      if (sc[2]) break;
      const int p = plist2[pi];
      hist[tid] = 0;
      __syncthreads();
      for (int i = tid; i < NS; i += NT) if (state[i] == 2){
        u32 oi = sIdx[i];
        int bb = (p >= 8) ? (int)(((~mono(pol[i])) >> ((p-8)*8)) & 255)
               : (p >= 4) ? (int)((keys32[oi] >> ((p-4)*8)) & 255)
               : (int)((((u32)oi) >> (p*8)) & 255);
        atomicAdd(&hist[bb], 1u);
      }
      __syncthreads();
      u32 myc = hist[tid], v = myc;
      { int l_ = tid & 63;
        #pragma unroll
        for (int s = 1; s < 64; s <<= 1){ u32 n = __shfl_up(v, s, 64); if (l_ >= s) v += n; }
        if (l_ == 63) wtot[tid >> 6] = v;
      }
      __syncthreads();
      bool iamp = false; u32 nk = 0;
      {
        u32 add = 0;
        #pragma unroll
        for (int w = 0; w < 4; ++w) if (w < (tid >> 6)) add += wtot[w];
        u32 myinc = v + add;
        u32 Krem = sc[0];
        u32 exc = myinc - myc;
        if (myc > 0 && exc <= Krem-1 && Krem-1 < myinc){ sc[1] = (u32)tid; iamp = true; nk = Krem - exc; }
      }
      __syncthreads();
      u32 pb = sc[1];
      for (int i = tid; i < NS; i += NT) if (state[i] == 2){
        u32 oi = sIdx[i];
        int bb = (p >= 8) ? (int)(((~mono(pol[i])) >> ((p-8)*8)) & 255)
               : (p >= 4) ? (int)((keys32[oi] >> ((p-4)*8)) & 255)
               : (int)((((u32)oi) >> (p*8)) & 255);
        state[i] = (bb < (int)pb) ? (u8)1 : (bb > (int)pb) ? (u8)0 : (u8)2;
      }
      if (iamp){ sc[0] = nk; if (nk == myc) sc[2] = 1; }
      __syncthreads();
    }
  }
  if (tid == 0) sc[4] = 0;
  __syncthreads();
  for (int i = tid; i < NS; i += NT) if (state[i] != 0){
    u32 pos = atomicAdd(&sc[4], 1u);
    list50[pos] = (u16)i;
  }
  __syncthreads();

  // ---------------- phase 5: single-wave bitonic-64 sort of the 50, write, L_end ----------------
  if (wv == 0){
    u64 hi; u32 lo; int s;
    if (lane < NO){
      s = (int)list50[lane];
      u32 oi = sIdx[s];
      hi = (((u64)(~mono(pol[s]))) << 32) | (u64)keys32[oi];
      lo = oi;
    } else { hi = 0xFFFFFFFFFFFFFFFFull; lo = 0xFFFFFFFFu; s = 0; }
    #pragma unroll
    for (int k = 2; k <= 64; k <<= 1){
      #pragma unroll
      for (int j = k >> 1; j > 0; j >>= 1){
        u64 ohi = __shfl_xor(hi, j, 64);
        u32 olo = __shfl_xor(lo, j, 64);
        int os  = __shfl_xor(s,  j, 64);
        bool up = ((lane & k) == 0);
        bool lower = ((lane & j) == 0);
        bool gt = (hi > ohi) || ((hi == ohi) && (lo > olo));
        bool lt = (hi < ohi) || ((hi == ohi) && (lo < olo));
        bool take = (up == lower) ? gt : lt;
        if (take){ hi = ohi; lo = olo; s = os; }
      }
    }
    float le = 0.f;
    if (lane < NO){
      float2 T = tg[s];
      out[2 + ((size_t)b*NO + lane)*2 + 0] = T.x;
      out[2 + ((size_t)b*NO + lane)*2 + 1] = T.y;
      le = sl1(T.x-ex) + sl1(T.y-ey);
    }
    #pragma unroll
    for (int o = 32; o > 0; o >>= 1) le += __shfl_down(le, o, 64);
    if (lane == 0){
      atomicAdd(&acc[2], (double)le);
      // ---- last-block finalize (single-dispatch graph) ----
      __threadfence();
      u32 old = atomicAdd(cnt, 1u);
      if (old == NB - 1){
        double c0 = atomicAdd(&acc[0], 0.0);
        double c1 = atomicAdd(&acc[1], 0.0);
        double c2 = atomicAdd(&acc[2], 0.0);
        out[0] = (float)(c0 / (double)NB);
        out[1] = (float)(c1 / ((double)NB*NS*2) + 3.0 * (c2 / ((double)NB*NO*2)));
      }
    }
  }
}

extern "C" void kernel_launch(void* const* d_in, const int* in_sizes, int n_in,
                              void* d_out, int out_size, void* d_ws, size_t ws_size,
                              hipStream_t stream){
  const float* osm   = (const float*)d_in[0];
  const float* agent = (const float*)d_in[1];
  const float* vect  = (const float*)d_in[2];
  const float* endp  = (const float*)d_in[3];
  // d_in[4] = speed (unused)
  const float* oxw1  = (const float*)d_in[5];
  const float* oxb1  = (const float*)d_in[6];
  const float* oxg1  = (const float*)d_in[7];
  const float* oxbe1 = (const float*)d_in[8];
  const float* oxw2  = (const float*)d_in[9];
  const float* oxb2  = (const float*)d_in[10];
  const float* tpw1  = (const float*)d_in[11];
  const float* tpb1  = (const float*)d_in[12];
  const float* tpg1  = (const float*)d_in[13];
  const float* tpbe1 = (const float*)d_in[14];
  const float* tpw2  = (const float*)d_in[15];
  const float* tpb2  = (const float*)d_in[16];
  const float* tpg2  = (const float*)d_in[17];
  const float* tpbe2 = (const float*)d_in[18];
  const float* tpw3  = (const float*)d_in[19];
  const float* tpb3  = (const float*)d_in[20];
  float* out = (float*)d_out;
  double* acc = (double*)d_ws;                 // acc[0..2], then u32 counter
  u32* cnt = (u32*)((char*)d_ws + 24);

  hipMemsetAsync(d_ws, 0, 32, stream);         // zero accumulators + arrival counter (capturable)
  hipLaunchKernelGGL(main_k, dim3(NB), dim3(NT), 0, stream,
    osm, agent, vect, endp,
    oxw1, oxb1, oxg1, oxbe1, oxw2, oxb2,
    tpw1, tpb1, tpg1, tpbe1, tpw2, tpb2, tpg2, tpbe2, tpw3, tpb3,
    out, acc, cnt);
}

// Round 8
// 321.093 us; speedup vs baseline: 1.0279x; 1.0279x over previous
//
#include <hip/hip_runtime.h>
#include <math.h>

#define NT 256
#define NW 4            // waves per block
#define NB 512
#define NP 2000
#define NS 1000
#define NO 50

typedef unsigned int u32;
typedef unsigned long long u64;
typedef unsigned short u16;
typedef unsigned char u8;
typedef __attribute__((ext_vector_type(8))) short short8;
typedef __attribute__((ext_vector_type(4))) float f32x4;

__device__ __forceinline__ float sl1(float x){ float d = fabsf(x); return d < 1.f ? 0.5f*d*d : d - 0.5f; }

__device__ __forceinline__ u32 mono(float f){
  u32 u = __float_as_uint(f);
  return u ^ ((u >> 31) ? 0xFFFFFFFFu : 0x80000000u);
}
// bitwise-exact vs jnp: mul, mul, add, sqrt all RN, no contraction
__device__ __forceinline__ float dist_rn(float x, float y){
  return __fsqrt_rn(__fadd_rn(__fmul_rn(x,x), __fmul_rn(y,y)));
}
__device__ __forceinline__ u16 f2bf(float f){           // RNE f32->bf16
  u32 u = __float_as_uint(f);
  u32 r = (u + 0x7FFFu + ((u >> 16) & 1u)) >> 16;
  return (u16)r;
}
__device__ __forceinline__ float bf2f(u16 h){ return __uint_as_float(((u32)h) << 16); }
// wave-uniform value -> SGPR
__device__ __forceinline__ float rfl(float v){
  return __builtin_bit_cast(float, __builtin_amdgcn_readfirstlane(__builtin_bit_cast(int, v)));
}

// gelu via Abramowitz-Stegun 7.1.26 erf (|eps| <= 1.5e-7), ~16 VALU
__device__ __forceinline__ float gelu_(float x){
  float z = x * 0.70710678118654752440f;
  float az = fabsf(z);
  float t = __frcp_rn(fmaf(0.3275911f, az, 1.0f));
  float p =          fmaf(t, 1.061405429f, -1.453152027f);
  p = fmaf(p, t, 1.421413741f);
  p = fmaf(p, t, -0.284496736f);
  p = fmaf(p, t, 0.254829592f);
  p = p * t;
  float e = __expf(-az*az);
  float er = fmaf(-p, e, 1.0f);
  er = copysignf(er, z);
  float hx = 0.5f * x;
  return fmaf(hx, er, hx);
}
__device__ __forceinline__ float wred(float v){  // full-wave sum
  #pragma unroll
  for (int s = 1; s < 64; s <<= 1) v += __shfl_xor(v, s, 64);
  return v;
}
__device__ __forceinline__ float bsum(float v, float* s, int tid){
  #pragma unroll
  for (int o = 32; o > 0; o >>= 1) v += __shfl_down(v, o, 64);
  __syncthreads();
  if ((tid & 63) == 0) s[tid >> 6] = v;
  __syncthreads();
  return (s[0]+s[1])+(s[2]+s[3]);
}
__device__ __forceinline__ float bmax(float v, float* s, int tid){
  #pragma unroll
  for (int o = 32; o > 0; o >>= 1) v = fmaxf(v, __shfl_down(v, o, 64));
  __syncthreads();
  if ((tid & 63) == 0) s[tid >> 6] = v;
  __syncthreads();
  return fmaxf(fmaxf(s[0],s[1]), fmaxf(s[2],s[3]));
}
__device__ __forceinline__ u32 bminu32(u32 v, u32* s, int tid){
  #pragma unroll
  for (int o = 32; o > 0; o >>= 1){ u32 w = __shfl_down(v, o, 64); v = w < v ? w : v; }
  __syncthreads();
  if ((tid & 63) == 0) s[tid >> 6] = v;
  __syncthreads();
  u32 a = s[0] < s[1] ? s[0] : s[1];
  u32 c = s[2] < s[3] ? s[2] : s[3];
  return a < c ? a : c;
}
__device__ __forceinline__ u64 bminu64(u64 v, u64* s, int tid){
  #pragma unroll
  for (int o = 32; o > 0; o >>= 1){ u64 w = __shfl_down(v, o, 64); v = w < v ? w : v; }
  __syncthreads();
  if ((tid & 63) == 0) s[tid >> 6] = v;
  __syncthreads();
  u64 a = s[0] < s[1] ? s[0] : s[1];
  u64 c = s[2] < s[3] ? s[2] : s[3];
  return a < c ? a : c;
}

// NOTE: no second __launch_bounds__ arg — on gfx950 it maps to min waves-per-EU
// and halves the unified VGPR/AGPR budget (64-VGPR cap -> 1 GB of spill traffic,
// measured rounds 4-5). Single arg only.
// Occupancy bands step at vgpr={64,128,256} (m69): 129..256 all give 2 waves/SIMD,
// so we spend the band on 2-tile ILP per wave instead of shaving registers.
__global__ __launch_bounds__(NT) void main_k(
    const float* __restrict__ osm, const float* __restrict__ agent, const float* __restrict__ vect,
    const float* __restrict__ endp,
    const float* __restrict__ oxw1, const float* __restrict__ oxb1, const float* __restrict__ oxg1, const float* __restrict__ oxbe1,
    const float* __restrict__ oxw2, const float* __restrict__ oxb2,
    const float* __restrict__ tpw1, const float* __restrict__ tpb1, const float* __restrict__ tpg1, const float* __restrict__ tpbe1,
    const float* __restrict__ tpw2, const float* __restrict__ tpb2, const float* __restrict__ tpg2, const float* __restrict__ tpbe2,
    const float* __restrict__ tpw3, const float* __restrict__ tpb3,
    float* __restrict__ out, double* __restrict__ acc, u32* __restrict__ cnt)
{
  const int b = blockIdx.x;
  const int tid = threadIdx.x;
  const int lane = tid & 63;
  const int wv = tid >> 6;
  const int lm = lane & 15;
  const int q  = lane >> 4;

  __shared__ u32 keys32[2048];       // mono(dist to origin) per original point
  __shared__ u8  state[2048];
  __shared__ u32 hist[256];
  __shared__ u32 wtot[NW];
  __shared__ u32 sc[8];              // 0:Krem 1:pivot 2:done 4:cnt 5:picked-s
  __shared__ u16 sIdx[1024];         // compacted s -> original point idx
  __shared__ float2 ptf2[NS];
  __shared__ float2 tg[NS];          // also reused as [8][64] f32 scratch in P1
  __shared__ float pol[NS];
  __shared__ float vfs[64], ats[64];
  // +4 pad entries (index c + (c>>4)) so the 4 q-group broadcast addrs hit distinct banks
  __shared__ float4 tabO[68];        // {foxA, foxB, foxC, oxbe1}
  __shared__ float2 tabW[68];        // {w2a, w2b}
  __shared__ float4 tabT[68];        // {ftpA, ftpB, ftpC, tpbe1}
  __shared__ float4 tabE[68];        // {tpg2, tpbe2, tpw3a, tpw3b}
  __shared__ float  tabB2[68];       // tpb2
  __shared__ float scox[6], sctp[6];
  __shared__ float redf[NW];
  __shared__ u32 redu[NW];
  __shared__ u64 redk[NW];
  __shared__ u16 list50[64];

  const float2* osm2 = (const float2*)osm;
  const float ex = endp[b*2 + 0], ey = endp[b*2 + 1];

  // ---------------- P0: batch vectors, distance keys, state init ----------------
  if (tid < 64){ vfs[tid] = vect[b*64 + tid]; ats[tid] = agent[b*64 + tid]; }
  for (int i = tid; i < NP; i += NT){
    float2 P = osm2[((size_t)b*NP + i)*2];
    keys32[i] = mono(dist_rn(P.x, P.y));
  }
  for (int i = tid; i < 2048; i += NT) state[i] = (i < NP) ? (u8)2 : (u8)0;
  if (tid == 0){ sc[0] = NS; sc[2] = 0; }
  __syncthreads();

  // ---------------- P1: bo/bt partials (feat = [vf, at], 4 groups x 32 k) ----------------
  {
    float* part = (float*)tg;   // [8][64]
    const int ch = tid & 63, grp = tid >> 6;
    float pox = 0.f, ptp = 0.f;
    for (int k = grp*32; k < grp*32 + 32; ++k){
      float f = (k < 64) ? vfs[k] : ats[k-64];
      pox = fmaf(f, oxw1[k*64 + ch], pox);
      ptp = fmaf(f, tpw1[k*64 + ch], ptp);
    }
    part[grp*64 + ch] = pox;
    part[(grp+4)*64 + ch] = ptp;
    __syncthreads();
    // ---------------- P2: closed-form LN folding (wave 0) ----------------
    if (tid < 64){
      const int pc = tid + (tid >> 4);     // padded table index
      float bo = oxb1[tid] + ((part[0*64+tid]+part[1*64+tid])+(part[2*64+tid]+part[3*64+tid]));
      float bt = tpb1[tid] + ((part[4*64+tid]+part[5*64+tid])+(part[6*64+tid]+part[7*64+tid]));
      float cxo = oxw1[128*64 + tid], cyo = oxw1[129*64 + tid];
      float cxt = tpw1[128*64 + tid], cyt = tpw1[129*64 + tid];
      const float inv64 = 1.0f/64.0f;
      float mb = wred(bo)*inv64, mx_ = wred(cxo)*inv64, my_ = wred(cyo)*inv64;
      float e0 = bo - mb, e1 = cxo - mx_, e2 = cyo - my_;
      float g = oxg1[tid];
      tabO[pc] = make_float4(e0*g, e1*g, e2*g, oxbe1[tid]);
      tabW[pc] = make_float2(oxw2[2*tid], oxw2[2*tid + 1]);
      tabE[pc] = make_float4(tpg2[tid], tpbe2[tid], tpw3[2*tid], tpw3[2*tid + 1]);
      tabB2[pc] = tpb2[tid];
      float E00 = wred(e0*e0)*inv64, E11 = wred(e1*e1)*inv64, E22 = wred(e2*e2)*inv64;
      float E01 = wred(e0*e1)*inv64, E02 = wred(e0*e2)*inv64, E12 = wred(e1*e2)*inv64;
      if (tid == 0){ scox[0]=E00; scox[1]=E11; scox[2]=E22; scox[3]=E01; scox[4]=E02; scox[5]=E12; }
      float mb2 = wred(bt)*inv64, mx2 = wred(cxt)*inv64, my2 = wred(cyt)*inv64;
      float f0 = bt - mb2, f1 = cxt - mx2, f2 = cyt - my2;
      float gt_ = tpg1[tid];
      tabT[pc] = make_float4(f0*gt_, f1*gt_, f2*gt_, tpbe1[tid]);
      float F00 = wred(f0*f0)*inv64, F11 = wred(f1*f1)*inv64, F22 = wred(f2*f2)*inv64;
      float F01 = wred(f0*f1)*inv64, F02 = wred(f0*f2)*inv64, F12 = wred(f1*f2)*inv64;
      if (tid == 0){ sctp[0]=F00; sctp[1]=F11; sctp[2]=F22; sctp[3]=F01; sctp[4]=F02; sctp[5]=F12; }
    }
  }
  __syncthreads();

  // ---------------- radix select #1: 1000 smallest by (mono(d), idx) ----------------
  {
    const int plist[6] = {7,6,5,4,1,0};
    for (int pi = 0; pi < 6; ++pi){
      if (sc[2]) break;
      const int p = plist[pi];
      hist[tid] = 0;
      __syncthreads();
      for (int i = tid; i < NP; i += NT) if (state[i] == 2){
        int bb = (p >= 4) ? (int)((keys32[i] >> ((p-4)*8)) & 255) : (int)((((u32)i) >> (p*8)) & 255);
        atomicAdd(&hist[bb], 1u);
      }
      __syncthreads();
      u32 myc = hist[tid], v = myc;
      { int l_ = tid & 63;
        #pragma unroll
        for (int s = 1; s < 64; s <<= 1){ u32 n = __shfl_up(v, s, 64); if (l_ >= s) v += n; }
        if (l_ == 63) wtot[tid >> 6] = v;
      }
      __syncthreads();
      bool iamp = false; u32 nk = 0;
      {
        u32 add = 0;
        #pragma unroll
        for (int w = 0; w < 4; ++w) if (w < (tid >> 6)) add += wtot[w];
        u32 myinc = v + add;
        u32 Krem = sc[0];
        u32 exc = myinc - myc;
        if (myc > 0 && exc <= Krem-1 && Krem-1 < myinc){ sc[1] = (u32)tid; iamp = true; nk = Krem - exc; }
      }
      __syncthreads();
      u32 pb = sc[1];
      for (int i = tid; i < NP; i += NT) if (state[i] == 2){
        int bb = (p >= 4) ? (int)((keys32[i] >> ((p-4)*8)) & 255) : (int)((((u32)i) >> (p*8)) & 255);
        state[i] = (bb < (int)pb) ? (u8)1 : (bb > (int)pb) ? (u8)0 : (u8)2;
      }
      if (iamp){ sc[0] = nk; if (nk == myc) sc[2] = 1; }
      __syncthreads();
    }
    // compact (selected = state != 0); order arbitrary by design
    if (tid == 0) sc[4] = 0;
    __syncthreads();
    for (int i = tid; i < NP; i += NT) if (state[i] != 0){
      u32 pos = atomicAdd(&sc[4], 1u);
      sIdx[pos] = (u16)i;
      ptf2[pos] = osm2[((size_t)b*NP + i)*2];
    }
    __syncthreads();
  }

  // ---------------- phase-2 wave-uniform scalars -> SGPRs ----------------
  const float so0 = rfl(scox[0]), so1 = rfl(scox[1]), so2 = rfl(scox[2]), so3 = rfl(scox[3]), so4 = rfl(scox[4]), so5 = rfl(scox[5]);
  const float st0 = rfl(sctp[0]), st1 = rfl(sctp[1]), st2 = rfl(sctp[2]), st3 = rfl(sctp[3]), st4 = rfl(sctp[4]), st5 = rfl(sctp[5]);
  const float oxb20 = rfl(oxb2[0]), oxb21 = rfl(oxb2[1]), tpb30 = rfl(tpb3[0]), tpb31 = rfl(tpb3[1]);
  // B fragments of tpw2 (split bf16: Bh + Bl), resident in VGPRs
  short8 bh[2][4], bl[2][4];
  #pragma unroll
  for (int kt = 0; kt < 2; ++kt)
    #pragma unroll
    for (int nt = 0; nt < 4; ++nt){
      short8 H, L;
      #pragma unroll
      for (int j = 0; j < 8; ++j){
        float w = tpw2[(kt*32 + q*8 + j)*64 + nt*16 + lm];
        u16 hh = f2bf(w);
        H[j] = (short)hh;
        L[j] = (short)f2bf(w - bf2f(hh));
      }
      bh[kt][nt] = H; bl[kt][nt] = L;
    }

  // ------- phase 2: MLP, A-layout direct, 2 tiles per wave-iteration (ILP x2) -------
  float loff = 0.f;
  for (int it = 0; it < 8; ++it){
    const int tA = wv + 8*it;            // 0..59
    const int tB = tA + 4;               // 4..63 (63 = dummy, stores guarded)
    const int pb2_[2] = { tA*16, tB*16 };
    float px[2], py[2];
    #pragma unroll
    for (int u = 0; u < 2; ++u){
      int sp = pb2_[u] + lm; if (sp > NS-1) sp = NS-1;
      const float2 P = ptf2[sp];
      px[u] = P.x; py[u] = P.y;
    }
    float r1[2], o0[2] = {0.f,0.f}, o1[2] = {0.f,0.f};
    #pragma unroll
    for (int u = 0; u < 2; ++u){
      float v1 = so0 + px[u]*px[u]*so1 + py[u]*py[u]*so2 + 2.0f*(px[u]*so3 + py[u]*so4 + px[u]*py[u]*so5);
      r1[u] = __frsqrt_rn(v1 + 1e-5f);
    }
    #pragma unroll
    for (int j = 0; j < 16; ++j){
      const int c = q*16 + j;
      const float4 T = tabO[c + (c>>4)];
      const float2 W = tabW[c + (c>>4)];
      #pragma unroll
      for (int u = 0; u < 2; ++u){
        float g1 = gelu_(fmaf(r1[u], fmaf(py[u], T.z, fmaf(px[u], T.y, T.x)), T.w));
        o0[u] = fmaf(g1, W.x, o0[u]);
        o1[u] = fmaf(g1, W.y, o1[u]);
      }
    }
    #pragma unroll
    for (int u = 0; u < 2; ++u){
      o0[u] += __shfl_xor(o0[u],16,64); o0[u] += __shfl_xor(o0[u],32,64);
      o1[u] += __shfl_xor(o1[u],16,64); o1[u] += __shfl_xor(o1[u],32,64);
    }
    float tx[2], ty[2], r2[2];
    #pragma unroll
    for (int u = 0; u < 2; ++u){
      tx[u] = px[u] + o0[u] + oxb20;
      ty[u] = py[u] + o1[u] + oxb21;
      float v2 = st0 + tx[u]*tx[u]*st1 + ty[u]*ty[u]*st2 + 2.0f*(tx[u]*st3 + ty[u]*st4 + tx[u]*ty[u]*st5);
      r2[u] = __frsqrt_rn(v2 + 1e-5f);
    }
    short8 ah0[2], ah1[2], al0[2], al1[2];
    #pragma unroll
    for (int j = 0; j < 8; ++j){
      const int c0 = q*8 + j, c1 = 32 + q*8 + j;
      const float4 T0 = tabT[c0 + (c0>>4)], T1 = tabT[c1 + (c1>>4)];
      #pragma unroll
      for (int u = 0; u < 2; ++u){
        float v0 = gelu_(fmaf(r2[u], fmaf(ty[u], T0.z, fmaf(tx[u], T0.y, T0.x)), T0.w));
        float v1 = gelu_(fmaf(r2[u], fmaf(ty[u], T1.z, fmaf(tx[u], T1.y, T1.x)), T1.w));
        u16 h0 = f2bf(v0), h1 = f2bf(v1);
        ah0[u][j] = (short)h0; al0[u][j] = (short)f2bf(v0 - bf2f(h0));
        ah1[u][j] = (short)h1; al1[u][j] = (short)f2bf(v1 - bf2f(h1));
      }
    }
    // 3-term split MFMA: h3 = g2 @ tpw2 + b2  (both tiles)
    f32x4 accv[2][4];
    #pragma unroll
    for (int nt = 0; nt < 4; ++nt){
      const int cb = lm + 16*nt;
      const float b2v = tabB2[cb + (cb>>4)];
      #pragma unroll
      for (int u = 0; u < 2; ++u){
        f32x4 c; c[0] = c[1] = c[2] = c[3] = b2v;
        c = __builtin_amdgcn_mfma_f32_16x16x32_bf16(ah0[u], bh[0][nt], c, 0,0,0);
        c = __builtin_amdgcn_mfma_f32_16x16x32_bf16(ah1[u], bh[1][nt], c, 0,0,0);
        c = __builtin_amdgcn_mfma_f32_16x16x32_bf16(ah0[u], bl[0][nt], c, 0,0,0);
        c = __builtin_amdgcn_mfma_f32_16x16x32_bf16(ah1[u], bl[1][nt], c, 0,0,0);
        c = __builtin_amdgcn_mfma_f32_16x16x32_bf16(al0[u], bh[0][nt], c, 0,0,0);
        c = __builtin_amdgcn_mfma_f32_16x16x32_bf16(al1[u], bh[1][nt], c, 0,0,0);
        accv[u][nt] = c;
      }
    }
    // epilogue in C-layout (row/point = q*4+e, col/channel = lm+16*nt), both tiles
    float sP[2][4], qP[2][4];
    #pragma unroll
    for (int u = 0; u < 2; ++u)
      #pragma unroll
      for (int e = 0; e < 4; ++e){
        float a0 = accv[u][0][e], a1 = accv[u][1][e], a2 = accv[u][2][e], a3 = accv[u][3][e];
        sP[u][e] = (a0+a1)+(a2+a3);
        qP[u][e] = fmaf(a0,a0, fmaf(a1,a1, fmaf(a2,a2, a3*a3)));
      }
    #pragma unroll
    for (int s_ = 1; s_ < 16; s_ <<= 1)
      #pragma unroll
      for (int u = 0; u < 2; ++u)
        #pragma unroll
        for (int e = 0; e < 4; ++e){ sP[u][e] += __shfl_xor(sP[u][e], s_, 64); qP[u][e] += __shfl_xor(qP[u][e], s_, 64); }
    float mE[2][4], rE[2][4];
    #pragma unroll
    for (int u = 0; u < 2; ++u)
      #pragma unroll
      for (int e = 0; e < 4; ++e){
        float m = sP[u][e] * (1.0f/64.0f);
        float vv = fmaf(sP[u][e], -m*(1.0f/64.0f), qP[u][e]*(1.0f/64.0f));
        mE[u][e] = m; rE[u][e] = __frsqrt_rn(vv + 1e-5f);
      }
    float uo[2][4] = {{0,0,0,0},{0,0,0,0}}, vo[2][4] = {{0,0,0,0},{0,0,0,0}};
    #pragma unroll
    for (int nt = 0; nt < 4; ++nt){
      const int cb = lm + 16*nt;
      const float4 E = tabE[cb + (cb>>4)];
      #pragma unroll
      for (int u = 0; u < 2; ++u)
        #pragma unroll
        for (int e = 0; e < 4; ++e){
          float g = gelu_(fmaf((accv[u][nt][e]-mE[u][e])*rE[u][e], E.x, E.y));
          uo[u][e] = fmaf(g, E.z, uo[u][e]);
          vo[u][e] = fmaf(g, E.w, vo[u][e]);
        }
    }
    #pragma unroll
    for (int s_ = 1; s_ < 16; s_ <<= 1)
      #pragma unroll
      for (int u = 0; u < 2; ++u)
        #pragma unroll
        for (int e = 0; e < 4; ++e){ uo[u][e] += __shfl_xor(uo[u][e], s_, 64); vo[u][e] += __shfl_xor(vo[u][e], s_, 64); }
    if (lm == 0){
      #pragma unroll
      for (int u = 0; u < 2; ++u)
        #pragma unroll
        for (int e = 0; e < 4; ++e){
          int pt = pb2_[u] + q*4 + e;
          if (pt < NS){
            float t0 = uo[u][e] + tpb30, t1 = vo[u][e] + tpb31;
            tg[pt] = make_float2(t0, t1);
            loff += sl1(t0-ex) + sl1(t1-ey);
          }
        }
    }
  }
  __syncthreads();

  // ---------------- phase 3/4: stats, policy, L_cls ----------------
  const float loffT = bsum(loff, redf, tid);
  float sx = 0.f, sy = 0.f;
  for (int s = tid; s < NS; s += NT){ float2 T = tg[s]; sx += T.x; sy += T.y; }
  const float mx = bsum(sx, redf, tid) * (1.0f/NS);
  const float my = bsum(sy, redf, tid) * (1.0f/NS);
  float qx = 0.f, qy = 0.f;
  for (int s = tid; s < NS; s += NT){ float2 T = tg[s]; float dx = T.x-mx, dy = T.y-my; qx = fmaf(dx,dx,qx); qy = fmaf(dy,dy,qy); }
  const float vx = bsum(qx, redf, tid) * (1.0f/(NS-1));
  const float vy = bsum(qy, redf, tid) * (1.0f/(NS-1));
  const float TWO_PI = 6.2831853071795864769f;
  const float rdx = __frcp_rn(__fsqrt_rn(TWO_PI*vx + 1e-6f));
  const float rdy = __frcp_rn(__fsqrt_rn(TWO_PI*vy + 1e-6f));
  float pmaxl = -1e30f;
  for (int s = tid; s < NS; s += NT){
    float2 T = tg[s]; float dx = T.x-mx, dy = T.y-my;
    float pdx = expf(-0.5f*dx*dx/vx + 1e-6f) * rdx;
    float pdy = expf(-0.5f*dy*dy/vy + 1e-6f) * rdy;
    float pp = pdx*pdy;
    pol[s] = pp;
    pmaxl = fmaxf(pmaxl, pp);
  }
  const float pmax = bmax(pmaxl, redf, tid);
  float se = 0.f;
  for (int s = tid; s < NS; s += NT) se += expf(pol[s] - pmax);
  const float sume = bsum(se, redf, tid);

  // target_index: exact argmax of -d/T with rank tie-break (3 scans)
  u32 xkm = 0xFFFFFFFFu;
  for (int s = tid; s < NS; s += NT){
    float2 Pp = ptf2[s];
    float dd = dist_rn(Pp.x-ex, Pp.y-ey);
    u32 xk = ~mono((0.0f - dd) / 0.01f);
    if (xk < xkm) xkm = xk;
  }
  xkm = bminu32(xkm, redu, tid);
  u64 dmin = 0xFFFFFFFFFFFFFFFFull;
  for (int s = tid; s < NS; s += NT){
    float2 Pp = ptf2[s];
    float dd = dist_rn(Pp.x-ex, Pp.y-ey);
    u32 xk = ~mono((0.0f - dd) / 0.01f);
    if (xk == xkm){ u32 oi = sIdx[s]; u64 dk = (((u64)keys32[oi]) << 32) | (u64)oi; if (dk < dmin) dmin = dk; }
  }
  dmin = bminu64(dmin, redk, tid);
  for (int s = tid; s < NS; s += NT){
    float2 Pp = ptf2[s];
    float dd = dist_rn(Pp.x-ex, Pp.y-ey);
    u32 xk = ~mono((0.0f - dd) / 0.01f);
    u32 oi = sIdx[s];
    if (xk == xkm && ((((u64)keys32[oi]) << 32) | (u64)oi) == dmin) sc[5] = (u32)s;
  }
  __syncthreads();
  if (tid == 0){
    float lse = pmax + logf(sume);
    float picked = pol[sc[5]];
    atomicAdd(&acc[0], (double)(lse - picked));
    atomicAdd(&acc[1], (double)loffT);
  }

  // ---------------- radix select #2: top-50 by (~mono(pol), mono(d), idx) ----------------
  for (int i = tid; i < 2048; i += NT) state[i] = (i < NS) ? (u8)2 : (u8)0;
  if (tid == 0){ sc[0] = NO; sc[2] = 0; }
  __syncthreads();
  {
    const int plist2[10] = {11,10,9,8,7,6,5,4,1,0};
    for (int pi = 0; pi < 10; ++pi){
      if (sc[2]) break;
      const int p = plist2[pi];
      hist[tid] = 0;
      __syncthreads();
      for (int i = tid; i < NS; i += NT) if (state[i] == 2){
        u32 oi = sIdx[i];
        int bb = (p >= 8) ? (int)(((~mono(pol[i])) >> ((p-8)*8)) & 255)
               : (p >= 4) ? (int)((keys32[oi] >> ((p-4)*8)) & 255)
               : (int)((((u32)oi) >> (p*8)) & 255);
        atomicAdd(&hist[bb], 1u);
      }
      __syncthreads();
      u32 myc = hist[tid], v = myc;
      { int l_ = tid & 63;
        #pragma unroll
        for (int s = 1; s < 64; s <<= 1){ u32 n = __shfl_up(v, s, 64); if (l_ >= s) v += n; }
        if (l_ == 63) wtot[tid >> 6] = v;
      }
      __syncthreads();
      bool iamp = false; u32 nk = 0;
      {
        u32 add = 0;
        #pragma unroll
        for (int w = 0; w < 4; ++w) if (w < (tid >> 6)) add += wtot[w];
        u32 myinc = v + add;
        u32 Krem = sc[0];
        u32 exc = myinc - myc;
        if (myc > 0 && exc <= Krem-1 && Krem-1 < myinc){ sc[1] = (u32)tid; iamp = true; nk = Krem - exc; }
      }
      __syncthreads();
      u32 pb = sc[1];
      for (int i = tid; i < NS; i += NT) if (state[i] == 2){
        u32 oi = sIdx[i];
        int bb = (p >= 8) ? (int)(((~mono(pol[i])) >> ((p-8)*8)) & 255)
               : (p >= 4) ? (int)((keys32[oi] >> ((p-4)*8)) & 255)
               : (int)((((u32)oi) >> (p*8)) & 255);
        state[i] = (bb < (int)pb) ? (u8)1 : (bb > (int)pb) ? (u8)0 : (u8)2;
      }
      if (iamp){ sc[0] = nk; if (nk == myc) sc[2] = 1; }
      __syncthreads();
    }
  }
  if (tid == 0) sc[4] = 0;
  __syncthreads();
  for (int i = tid; i < NS; i += NT) if (state[i] != 0){
    u32 pos = atomicAdd(&sc[4], 1u);
    list50[pos] = (u16)i;
  }
  __syncthreads();

  // ---------------- phase 5: single-wave bitonic-64 sort of the 50, write, L_end ----------------
  if (wv == 0){
    u64 hi; u32 lo; int s;
    if (lane < NO){
      s = (int)list50[lane];
      u32 oi = sIdx[s];
      hi = (((u64)(~mono(pol[s]))) << 32) | (u64)keys32[oi];
      lo = oi;
    } else { hi = 0xFFFFFFFFFFFFFFFFull; lo = 0xFFFFFFFFu; s = 0; }
    #pragma unroll
    for (int k = 2; k <= 64; k <<= 1){
      #pragma unroll
      for (int j = k >> 1; j > 0; j >>= 1){
        u64 ohi = __shfl_xor(hi, j, 64);
        u32 olo = __shfl_xor(lo, j, 64);
        int os  = __shfl_xor(s,  j, 64);
        bool up = ((lane & k) == 0);
        bool lower = ((lane & j) == 0);
        bool gt = (hi > ohi) || ((hi == ohi) && (lo > olo));
        bool lt = (hi < ohi) || ((hi == ohi) && (lo < olo));
        bool take = (up == lower) ? gt : lt;
        if (take){ hi = ohi; lo = olo; s = os; }
      }
    }
    float le = 0.f;
    if (lane < NO){
      float2 T = tg[s];
      out[2 + ((size_t)b*NO + lane)*2 + 0] = T.x;
      out[2 + ((size_t)b*NO + lane)*2 + 1] = T.y;
      le = sl1(T.x-ex) + sl1(T.y-ey);
    }
    #pragma unroll
    for (int o = 32; o > 0; o >>= 1) le += __shfl_down(le, o, 64);
    if (lane == 0){
      atomicAdd(&acc[2], (double)le);
      // ---- last-block finalize (single-dispatch graph) ----
      __threadfence();
      u32 old = atomicAdd(cnt, 1u);
      if (old == NB - 1){
        double c0 = atomicAdd(&acc[0], 0.0);
        double c1 = atomicAdd(&acc[1], 0.0);
        double c2 = atomicAdd(&acc[2], 0.0);
        out[0] = (float)(c0 / (double)NB);
        out[1] = (float)(c1 / ((double)NB*NS*2) + 3.0 * (c2 / ((double)NB*NO*2)));
      }
    }
  }
}

extern "C" void kernel_launch(void* const* d_in, const int* in_sizes, int n_in,
                              void* d_out, int out_size, void* d_ws, size_t ws_size,
                              hipStream_t stream){
  const float* osm   = (const float*)d_in[0];
  const float* agent = (const float*)d_in[1];
  const float* vect  = (const float*)d_in[2];
  const float* endp  = (const float*)d_in[3];
  // d_in[4] = speed (unused)
  const float* oxw1  = (const float*)d_in[5];
  const float* oxb1  = (const float*)d_in[6];
  const float* oxg1  = (const float*)d_in[7];
  const float* oxbe1 = (const float*)d_in[8];
  const float* oxw2  = (const float*)d_in[9];
  const float* oxb2  = (const float*)d_in[10];
  const float* tpw1  = (const float*)d_in[11];
  const float* tpb1  = (const float*)d_in[12];
  const float* tpg1  = (const float*)d_in[13];
  const float* tpbe1 = (const float*)d_in[14];
  const float* tpw2  = (const float*)d_in[15];
  const float* tpb2  = (const float*)d_in[16];
  const float* tpg2  = (const float*)d_in[17];
  const float* tpbe2 = (const float*)d_in[18];
  const float* tpw3  = (const float*)d_in[19];
  const float* tpb3  = (const float*)d_in[20];
  float* out = (float*)d_out;
  double* acc = (double*)d_ws;                 // acc[0..2], then u32 counter
  u32* cnt = (u32*)((char*)d_ws + 24);

  hipMemsetAsync(d_ws, 0, 32, stream);         // zero accumulators + arrival counter (capturable)
  hipLaunchKernelGGL(main_k, dim3(NB), dim3(NT), 0, stream,
    osm, agent, vect, endp,
    oxw1, oxb1, oxg1, oxbe1, oxw2, oxb2,
    tpw1, tpb1, tpg1, tpbe1, tpw2, tpb2, tpg2, tpbe2, tpw3, tpb3,
    out, acc, cnt);
}